// Round 1
// baseline (38.892 us; speedup 1.0000x reference)
//
#include <hip/hip_runtime.h>

// Problem constants (reference: shape (32, 3, 512, 512) float32).
#define HW      (512 * 512)        // 262144 elements per channel plane
#define NBATCH  32
#define NPIX    (NBATCH * HW)      // 8,388,608 pixels per tensor
#define NGROUP  (NPIX / 4)         // 2,097,152 float4 pixel-groups
#define NBLOCKS 2048
#define NTHREADS 256

__device__ __forceinline__ float saturation(float x_r, float x_g, float x_b) {
    // rgb = (x + 1) * 0.5 in [0,1]; S = (max - min) / max, 0 where max == 0
    float r = (x_r + 1.0f) * 0.5f;
    float g = (x_g + 1.0f) * 0.5f;
    float b = (x_b + 1.0f) * 0.5f;
    float v  = fmaxf(fmaxf(r, g), b);
    float mn = fminf(fminf(r, g), b);
    float d  = v - mn;
    return (v > 0.0f) ? (d / v) : 0.0f;
}

__global__ __launch_bounds__(NTHREADS) void sat_loss_partial(
        const float* __restrict__ gen,
        const float* __restrict__ tgt,
        float* __restrict__ partial) {
    const int tid = blockIdx.x * blockDim.x + threadIdx.x;
    const int stride = gridDim.x * blockDim.x;

    float acc = 0.0f;
    for (int g = tid; g < NGROUP; g += stride) {
        const int b = g >> 16;                 // g / (HW/4), HW/4 == 65536
        const long r = (long)(g & 65535) << 2; // element offset within plane
        const long base = (long)b * (3L * HW) + r;

        const float4 ar = *(const float4*)(gen + base);
        const float4 ag = *(const float4*)(gen + base + HW);
        const float4 ab = *(const float4*)(gen + base + 2L * HW);
        const float4 br = *(const float4*)(tgt + base);
        const float4 bg = *(const float4*)(tgt + base + HW);
        const float4 bb = *(const float4*)(tgt + base + 2L * HW);

        acc += fabsf(saturation(ar.x, ag.x, ab.x) - saturation(br.x, bg.x, bb.x));
        acc += fabsf(saturation(ar.y, ag.y, ab.y) - saturation(br.y, bg.y, bb.y));
        acc += fabsf(saturation(ar.z, ag.z, ab.z) - saturation(br.z, bg.z, bb.z));
        acc += fabsf(saturation(ar.w, ag.w, ab.w) - saturation(br.w, bg.w, bb.w));
    }

    // wave-64 butterfly reduce
    #pragma unroll
    for (int off = 32; off > 0; off >>= 1)
        acc += __shfl_down(acc, off, 64);

    __shared__ float wave_sum[NTHREADS / 64];
    const int lane = threadIdx.x & 63;
    const int wid  = threadIdx.x >> 6;
    if (lane == 0) wave_sum[wid] = acc;
    __syncthreads();

    if (threadIdx.x == 0) {
        float s = 0.0f;
        #pragma unroll
        for (int i = 0; i < NTHREADS / 64; ++i) s += wave_sum[i];
        partial[blockIdx.x] = s;
    }
}

__global__ __launch_bounds__(NTHREADS) void sat_loss_finalize(
        const float* __restrict__ partial,
        float* __restrict__ out) {
    float acc = 0.0f;
    for (int i = threadIdx.x; i < NBLOCKS; i += NTHREADS)
        acc += partial[i];

    #pragma unroll
    for (int off = 32; off > 0; off >>= 1)
        acc += __shfl_down(acc, off, 64);

    __shared__ float wave_sum[NTHREADS / 64];
    const int lane = threadIdx.x & 63;
    const int wid  = threadIdx.x >> 6;
    if (lane == 0) wave_sum[wid] = acc;
    __syncthreads();

    if (threadIdx.x == 0) {
        float s = 0.0f;
        #pragma unroll
        for (int i = 0; i < NTHREADS / 64; ++i) s += wave_sum[i];
        out[0] = s * (1.0f / (float)NPIX);   // WEIGHT == 1.0
    }
}

extern "C" void kernel_launch(void* const* d_in, const int* in_sizes, int n_in,
                              void* d_out, int out_size, void* d_ws, size_t ws_size,
                              hipStream_t stream) {
    const float* gen = (const float*)d_in[0];
    const float* tgt = (const float*)d_in[1];
    float* out = (float*)d_out;
    float* partial = (float*)d_ws;   // NBLOCKS floats = 8 KiB of scratch

    sat_loss_partial<<<NBLOCKS, NTHREADS, 0, stream>>>(gen, tgt, partial);
    sat_loss_finalize<<<1, NTHREADS, 0, stream>>>(partial, out);
}